// Round 1
// baseline (309.748 us; speedup 1.0000x reference)
//
#include <hip/hip_runtime.h>
#include <hip/hip_bf16.h>
#include <cstdint>
#include <cstddef>

#define NB 8
#define NL 1024
#define NT 1024
#define ND 768
#define NH 12
#define NDH 64
#define NM (NB*NL)   // 8192 rows for the projection GEMMs

typedef short short8 __attribute__((ext_vector_type(8)));
typedef unsigned short ushort8v __attribute__((ext_vector_type(8)));
typedef unsigned short ushort4v __attribute__((ext_vector_type(4)));
typedef float f32x4 __attribute__((ext_vector_type(4)));
typedef float float4v __attribute__((ext_vector_type(4)));

__device__ __forceinline__ unsigned short f2bf(float f) {
  union { __hip_bfloat16 h; unsigned short u; } cv;
  cv.h = __float2bfloat16(f);
  return cv.u;
}

// ---------------------------------------------------------------------------
// Weight convert+transpose: Wt[z][n][k] = bf16(W[z][k][n]), z in {q,k,v,o}
// ---------------------------------------------------------------------------
__global__ __launch_bounds__(256) void wt_kernel(
    const float* __restrict__ W0, const float* __restrict__ W1,
    const float* __restrict__ W2, const float* __restrict__ W3,
    unsigned short* __restrict__ Wt) {
  __shared__ float tile[32][33];
  const float* W = blockIdx.z == 0 ? W0 : blockIdx.z == 1 ? W1 : blockIdx.z == 2 ? W2 : W3;
  const int k0 = blockIdx.x * 32, n0 = blockIdx.y * 32;
  const int tx = threadIdx.x & 31, ty = threadIdx.x >> 5;
  for (int r = ty; r < 32; r += 8) tile[r][tx] = W[(size_t)(k0 + r) * ND + n0 + tx];
  __syncthreads();
  unsigned short* out = Wt + (size_t)blockIdx.z * ND * ND;
  for (int r = ty; r < 32; r += 8) out[(size_t)(n0 + r) * ND + k0 + tx] = f2bf(tile[tx][r]);
}

// ---------------------------------------------------------------------------
// GEMM: C[M][N] = (A[M][K] @ Bt[N][K]^T + bias[N]) * scale
// A: fp32 (A_F32=1) or bf16 (A_F32=0). C: fp32 (OUT_F32=1) or bf16.
// 128x128 tile, BK=32, 4 waves each computing a 64x64 quadrant via 4x4
// mfma_f32_16x16x32_bf16 fragments.
// ---------------------------------------------------------------------------
template<int A_F32, int OUT_F32>
__global__ __launch_bounds__(256) void gemm_kernel(
    const void* __restrict__ Av, const unsigned short* __restrict__ Bt,
    const float* __restrict__ bias, void* __restrict__ Cv,
    int M, int N, int K, float scale) {
  __shared__ __align__(16) unsigned short As[128][40];
  __shared__ __align__(16) unsigned short Bs[128][40];
  const int tid = threadIdx.x;
  const int lane = tid & 63, w = tid >> 6;
  const int wrow = w & 1, wcol = w >> 1;
  const int c = lane & 15, g = lane >> 4;
  const int mbase = blockIdx.x * 128, nbase = blockIdx.y * 128;

  f32x4 acc[4][4];
#pragma unroll
  for (int m = 0; m < 4; m++)
#pragma unroll
    for (int n = 0; n < 4; n++) acc[m][n] = (f32x4){0.f, 0.f, 0.f, 0.f};

  for (int k0 = 0; k0 < K; k0 += 32) {
    if (A_F32) {
      const float* A = (const float*)Av;
      const int kq = tid & 7, row = tid >> 3;  // 8 float4 per 32-wide k row
#pragma unroll
      for (int rr = row; rr < 128; rr += 32) {
        float4v x = *(const float4v*)&A[(size_t)(mbase + rr) * K + k0 + kq * 4];
        ushort4v y;
#pragma unroll
        for (int i = 0; i < 4; i++) y[i] = f2bf(x[i]);
        *(ushort4v*)&As[rr][kq * 4] = y;
      }
    } else {
      const unsigned short* A = (const unsigned short*)Av;
      const int kq = tid & 3, row = tid >> 2;
#pragma unroll
      for (int rr = row; rr < 128; rr += 64)
        *(ushort8v*)&As[rr][kq * 8] =
            *(const ushort8v*)&A[(size_t)(mbase + rr) * K + k0 + kq * 8];
    }
    {
      const int kq = tid & 3, row = tid >> 2;
#pragma unroll
      for (int rr = row; rr < 128; rr += 64)
        *(ushort8v*)&Bs[rr][kq * 8] =
            *(const ushort8v*)&Bt[(size_t)(nbase + rr) * K + k0 + kq * 8];
    }
    __syncthreads();

    short8 a[4], b[4];
#pragma unroll
    for (int m = 0; m < 4; m++) a[m] = *(const short8*)&As[wrow * 64 + m * 16 + c][g * 8];
#pragma unroll
    for (int n = 0; n < 4; n++) b[n] = *(const short8*)&Bs[wcol * 64 + n * 16 + c][g * 8];
#pragma unroll
    for (int m = 0; m < 4; m++)
#pragma unroll
      for (int n = 0; n < 4; n++)
        acc[m][n] = __builtin_amdgcn_mfma_f32_16x16x32_bf16(a[m], b[n], acc[m][n], 0, 0, 0);
    __syncthreads();
  }

#pragma unroll
  for (int n = 0; n < 4; n++) {
    const int col = nbase + wcol * 64 + n * 16 + c;
    const float bv = bias[col];
#pragma unroll
    for (int m = 0; m < 4; m++) {
      const int row0 = mbase + wrow * 64 + m * 16 + g * 4;
#pragma unroll
      for (int j = 0; j < 4; j++) {
        float y2 = (acc[m][n][j] + bv) * scale;
        if (OUT_F32)
          ((float*)Cv)[(size_t)(row0 + j) * N + col] = y2;
        else
          ((unsigned short*)Cv)[(size_t)(row0 + j) * N + col] = f2bf(y2);
      }
    }
  }
}

// ---------------------------------------------------------------------------
// Flash attention over bf16 qh/kh/vh ([B*1024][768] with head h at col h*64).
// Block: 256 threads = 4 waves; each block does 64 q-rows of one (b,h);
// each wave owns 16 q-rows. KV tiles of 64, online softmax in the MFMA C
// layout (col=lane&15, row=(lane>>4)*4+j); row-reduce via shfl_xor over the
// 16-lane column group. V staged transposed in LDS with XOR swizzle.
// ---------------------------------------------------------------------------
__global__ __launch_bounds__(256) void attn_kernel(
    const unsigned short* __restrict__ qh, const unsigned short* __restrict__ kh,
    const unsigned short* __restrict__ vh, const unsigned int* __restrict__ mask,
    unsigned short* __restrict__ ao) {
  __shared__ __align__(16) unsigned short Ks[64][72];
  __shared__ __align__(16) unsigned short Vs[64][72];  // [d][t^swz]
  __shared__ __align__(16) unsigned short Ps[64][72];
  const int tid = threadIdx.x;
  const int lane = tid & 63, w = tid >> 6;
  const int c = lane & 15, g = lane >> 4;
  const int qb = blockIdx.x * 64;
  const int b = blockIdx.y / NH, h = blockIdx.y % NH;

  short8 aq[2];
  {
    size_t base = (size_t)(b * NL + qb + w * 16 + c) * ND + h * NDH;
    aq[0] = *(const short8*)&qh[base + g * 8];
    aq[1] = *(const short8*)&qh[base + 32 + g * 8];
  }

  f32x4 o[4];
#pragma unroll
  for (int n2 = 0; n2 < 4; n2++) o[n2] = (f32x4){0.f, 0.f, 0.f, 0.f};
  float mrun[4] = {-1e30f, -1e30f, -1e30f, -1e30f};
  float lrun[4] = {0.f, 0.f, 0.f, 0.f};

  const int dq = tid & 7, tr = tid >> 3;

  for (int t0 = 0; t0 < NT; t0 += 64) {
    // ---- stage K (row-major) and V (transposed+swizzled)
#pragma unroll
    for (int t = tr; t < 64; t += 32) {
      size_t src = (size_t)(b * NT + t0 + t) * ND + h * NDH + dq * 8;
      *(ushort8v*)&Ks[t][dq * 8] = *(const ushort8v*)&kh[src];
      ushort8v vv = *(const ushort8v*)&vh[src];
#pragma unroll
      for (int i = 0; i < 8; i++) {
        int d = dq * 8 + i;
        Vs[d][t ^ (((d >> 3) & 7) << 3)] = vv[i];
      }
    }
    __syncthreads();

    // ---- S = Q K^T  (wave's 16 rows x 64 cols)
    f32x4 s[4];
#pragma unroll
    for (int n = 0; n < 4; n++) s[n] = (f32x4){0.f, 0.f, 0.f, 0.f};
#pragma unroll
    for (int ks = 0; ks < 2; ks++)
#pragma unroll
      for (int n = 0; n < 4; n++) {
        short8 bk = *(const short8*)&Ks[n * 16 + c][ks * 32 + g * 8];
        s[n] = __builtin_amdgcn_mfma_f32_16x16x32_bf16(aq[ks], bk, s[n], 0, 0, 0);
      }

    // ---- mask + tile row-max
    float mt[4] = {-1e30f, -1e30f, -1e30f, -1e30f};
#pragma unroll
    for (int n = 0; n < 4; n++) {
      bool msk = mask[(size_t)b * NT + t0 + n * 16 + c] != 0u;
      if (msk) {
#pragma unroll
        for (int j = 0; j < 4; j++) s[n][j] = -INFINITY;
      } else {
#pragma unroll
        for (int j = 0; j < 4; j++) mt[j] = fmaxf(mt[j], s[n][j]);
      }
    }
#pragma unroll
    for (int off = 1; off < 16; off <<= 1)
#pragma unroll
      for (int j = 0; j < 4; j++) mt[j] = fmaxf(mt[j], __shfl_xor(mt[j], off, 64));

    // ---- online softmax update
    float alpha[4], rs[4];
#pragma unroll
    for (int j = 0; j < 4; j++) {
      float mnew = fmaxf(mrun[j], mt[j]);
      alpha[j] = __expf(mrun[j] - mnew);
      mrun[j] = mnew;
      rs[j] = 0.f;
    }
#pragma unroll
    for (int n = 0; n < 4; n++)
#pragma unroll
      for (int j = 0; j < 4; j++) {
        float p = __expf(s[n][j] - mrun[j]);
        s[n][j] = p;
        rs[j] += p;
      }
#pragma unroll
    for (int off = 1; off < 16; off <<= 1)
#pragma unroll
      for (int j = 0; j < 4; j++) rs[j] += __shfl_xor(rs[j], off, 64);
#pragma unroll
    for (int j = 0; j < 4; j++) lrun[j] = lrun[j] * alpha[j] + rs[j];
#pragma unroll
    for (int n2 = 0; n2 < 4; n2++)
#pragma unroll
      for (int j = 0; j < 4; j++) o[n2][j] *= alpha[j];

    // ---- P -> bf16 via LDS (re-fragment for PV); rows are wave-private
#pragma unroll
    for (int n = 0; n < 4; n++)
#pragma unroll
      for (int j = 0; j < 4; j++) Ps[w * 16 + g * 4 + j][n * 16 + c] = f2bf(s[n][j]);

    // ---- O += P V
#pragma unroll
    for (int ks = 0; ks < 2; ks++) {
      short8 ap = *(const short8*)&Ps[w * 16 + c][ks * 32 + g * 8];
#pragma unroll
      for (int n2 = 0; n2 < 4; n2++) {
        int d = n2 * 16 + c;
        int tb = (ks * 32 + g * 8) ^ (((d >> 3) & 7) << 3);
        short8 bv2 = *(const short8*)&Vs[d][tb];
        o[n2] = __builtin_amdgcn_mfma_f32_16x16x32_bf16(ap, bv2, o[n2], 0, 0, 0);
      }
    }
    __syncthreads();
  }

  // ---- epilogue: O / l -> bf16 attnout
#pragma unroll
  for (int j = 0; j < 4; j++) {
    float inv = 1.f / lrun[j];
    size_t row = (size_t)(b * NL + qb + w * 16 + g * 4 + j) * ND + h * NDH;
#pragma unroll
    for (int n2 = 0; n2 < 4; n2++) ao[row + n2 * 16 + c] = f2bf(o[n2][j] * inv);
  }
}

// ---------------------------------------------------------------------------
extern "C" void kernel_launch(void* const* d_in, const int* in_sizes, int n_in,
                              void* d_out, int out_size, void* d_ws, size_t ws_size,
                              hipStream_t stream) {
  const float* q  = (const float*)d_in[0];
  const float* k  = (const float*)d_in[1];
  const float* v  = (const float*)d_in[2];
  // d_in[3] = pairwise_locs: unused in the reference forward path
  const unsigned int* mask = (const unsigned int*)d_in[4];  // nonzero word = padded
  const float* Wq = (const float*)d_in[5];
  const float* bq = (const float*)d_in[6];
  const float* Wk = (const float*)d_in[7];
  const float* bk = (const float*)d_in[8];
  const float* Wv = (const float*)d_in[9];
  const float* bv = (const float*)d_in[10];
  const float* Wo = (const float*)d_in[11];
  const float* bo = (const float*)d_in[12];
  float* out = (float*)d_out;

  unsigned short* ws  = (unsigned short*)d_ws;
  unsigned short* Wt  = ws;                               // 4 * 768*768 bf16
  unsigned short* qhb = Wt + (size_t)4 * ND * ND;         // 8192*768 bf16
  unsigned short* khb = qhb + (size_t)NM * ND;
  unsigned short* vhb = khb + (size_t)NM * ND;
  unsigned short* aob = vhb + (size_t)NM * ND;

  wt_kernel<<<dim3(ND / 32, ND / 32, 4), 256, 0, stream>>>(Wq, Wk, Wv, Wo, Wt);

  dim3 ggrid(NM / 128, ND / 128);
  // qh scaled by 1/sqrt(DH) here so attention needs no extra scale
  gemm_kernel<1, 0><<<ggrid, 256, 0, stream>>>(q, Wt, bq, qhb, NM, ND, ND, 0.125f);
  gemm_kernel<1, 0><<<ggrid, 256, 0, stream>>>(k, Wt + (size_t)ND * ND, bk, khb, NM, ND, ND, 1.0f);
  gemm_kernel<1, 0><<<ggrid, 256, 0, stream>>>(v, Wt + (size_t)2 * ND * ND, bv, vhb, NM, ND, ND, 1.0f);

  attn_kernel<<<dim3(NL / 64, NB * NH), 256, 0, stream>>>(qhb, khb, vhb, mask, aob);

  gemm_kernel<0, 1><<<ggrid, 256, 0, stream>>>(aob, Wt + (size_t)3 * ND * ND, bo, out, NM, ND, ND, 1.0f);
}

// Round 2
// 160.642 us; speedup vs baseline: 1.9282x; 1.9282x over previous
//
#include <hip/hip_runtime.h>
#include <hip/hip_bf16.h>
#include <cstdint>
#include <cstddef>

#define NB 8
#define NL 1024
#define NT 1024
#define ND 768
#define NH 12
#define NDH 64
#define NM (NB*NL)

typedef short short8 __attribute__((ext_vector_type(8)));
typedef unsigned short ushort4v __attribute__((ext_vector_type(4)));
typedef unsigned int uint4v __attribute__((ext_vector_type(4)));
typedef float f32x4 __attribute__((ext_vector_type(4)));
typedef float float4v __attribute__((ext_vector_type(4)));

__device__ __forceinline__ unsigned short f2bf(float f) {
  union { __hip_bfloat16 h; unsigned short u; } cv;
  cv.h = __float2bfloat16(f);
  return cv.u;
}
__device__ __forceinline__ unsigned pk2(float lo, float hi) {
  return (unsigned)f2bf(lo) | ((unsigned)f2bf(hi) << 16);
}
// async global->LDS, 16B per lane; LDS dest = wave-uniform base + lane*16
__device__ __forceinline__ void gll16(const void* g, void* l) {
  __builtin_amdgcn_global_load_lds(
      (const __attribute__((address_space(1))) unsigned int*)g,
      (__attribute__((address_space(3))) unsigned int*)l, 16, 0, 0);
}

// ---------------------------------------------------------------------------
// Weight convert+transpose: Wt[z][n][k] = bf16(W[z][k][n]), z in {q,k,v,o}
// ---------------------------------------------------------------------------
__global__ __launch_bounds__(256) void wt_kernel(
    const float* __restrict__ W0, const float* __restrict__ W1,
    const float* __restrict__ W2, const float* __restrict__ W3,
    unsigned short* __restrict__ Wt) {
  __shared__ float tile[32][33];
  const float* W = blockIdx.z == 0 ? W0 : blockIdx.z == 1 ? W1 : blockIdx.z == 2 ? W2 : W3;
  const int k0 = blockIdx.x * 32, n0 = blockIdx.y * 32;
  const int tx = threadIdx.x & 31, ty = threadIdx.x >> 5;
  for (int r = ty; r < 32; r += 8) tile[r][tx] = W[(size_t)(k0 + r) * ND + n0 + tx];
  __syncthreads();
  unsigned short* out = Wt + (size_t)blockIdx.z * ND * ND;
  for (int r = ty; r < 32; r += 8) out[(size_t)(n0 + r) * ND + k0 + tx] = f2bf(tile[tx][r]);
}

// ---------------------------------------------------------------------------
// GEMM 128x128 tile, BK=64, 4 waves, 4x4 16x16x32 frags, swizzled LDS.
// PROJ=1: A = {q,k,v}[z] fp32 (reg-staged+converted); out bf16; z==0 scaled
//         by 1/8; z==2 written transposed per-head as vhT[(b*NH+h)*64+d][t].
// PROJ=0: A = aob bf16 (global_load_lds); out fp32 + bias (Wo path).
// LDS layout: [row][chunk ^ (row&7)], chunk = 16B (8 bf16).
// ---------------------------------------------------------------------------
template<int PROJ>
__global__ __launch_bounds__(256) void gemm_kernel(
    const float* __restrict__ qf, const float* __restrict__ kf,
    const float* __restrict__ vf, const unsigned short* __restrict__ aob,
    const unsigned short* __restrict__ Wt,
    const float* __restrict__ b0, const float* __restrict__ b1,
    const float* __restrict__ b2, const float* __restrict__ b3,
    unsigned short* __restrict__ qhb, unsigned short* __restrict__ khb,
    unsigned short* __restrict__ vhT, float* __restrict__ outf) {
  __shared__ __align__(16) unsigned short As[128 * 64];
  __shared__ __align__(16) unsigned short Bs[128 * 64];
  const int tid = threadIdx.x, lane = tid & 63, w = tid >> 6;
  const int c = lane & 15, g = lane >> 4;
  const int wrow = w & 1, wcol = w >> 1;
  const int l8 = lane >> 3, l7 = lane & 7, csw = l7 ^ l8;
  const int mbase = blockIdx.x * 128, nbase = blockIdx.y * 128;
  const int z = PROJ ? blockIdx.z : 3;

  const float* Af = PROJ ? (z == 0 ? qf : z == 1 ? kf : vf) : nullptr;
  const unsigned short* Bt = Wt + (size_t)z * ND * ND;
  const float* bias = z == 0 ? b0 : z == 1 ? b1 : z == 2 ? b2 : b3;

  f32x4 acc[4][4];
#pragma unroll
  for (int m = 0; m < 4; m++)
#pragma unroll
    for (int n = 0; n < 4; n++) acc[m][n] = (f32x4){0.f, 0.f, 0.f, 0.f};

  for (int k0 = 0; k0 < ND; k0 += 64) {
    if (PROJ) {
      // reg-stage fp32 -> bf16, 4 chunks (16B) per thread, swizzled write
#pragma unroll
      for (int i = 0; i < 4; i++) {
        int id = i * 256 + tid;          // chunk id 0..1023
        int r = id >> 3, cc = id & 7;
        const float* src = &Af[(size_t)(mbase + r) * ND + k0 + cc * 8];
        float4v x0 = *(const float4v*)src;
        float4v x1 = *(const float4v*)(src + 4);
        uint4v y = {pk2(x0[0], x0[1]), pk2(x0[2], x0[3]),
                    pk2(x1[0], x1[1]), pk2(x1[2], x1[3])};
        *(uint4v*)&As[r * 64 + ((cc ^ (r & 7)) * 8)] = y;
      }
    } else {
#pragma unroll
      for (int it = 0; it < 4; it++) {
        int r = it * 32 + w * 8 + l8;
        gll16(&aob[(size_t)(mbase + r) * ND + k0 + csw * 8],
              &As[(it * 32 + w * 8) * 64]);
      }
    }
#pragma unroll
    for (int it = 0; it < 4; it++) {
      int r = it * 32 + w * 8 + l8;
      gll16(&Bt[(size_t)(nbase + r) * ND + k0 + csw * 8],
            &Bs[(it * 32 + w * 8) * 64]);
    }
    __syncthreads();

#pragma unroll
    for (int ks = 0; ks < 2; ks++) {
      short8 a[4], b[4];
#pragma unroll
      for (int m = 0; m < 4; m++) {
        int r = wrow * 64 + m * 16 + c;
        a[m] = *(const short8*)&As[r * 64 + (((ks * 4 + g) ^ (c & 7)) * 8)];
      }
#pragma unroll
      for (int n = 0; n < 4; n++) {
        int r = wcol * 64 + n * 16 + c;
        b[n] = *(const short8*)&Bs[r * 64 + (((ks * 4 + g) ^ (c & 7)) * 8)];
      }
#pragma unroll
      for (int m = 0; m < 4; m++)
#pragma unroll
        for (int n = 0; n < 4; n++)
          acc[m][n] = __builtin_amdgcn_mfma_f32_16x16x32_bf16(a[m], b[n], acc[m][n], 0, 0, 0);
    }
    __syncthreads();
  }

  // epilogue
#pragma unroll
  for (int n = 0; n < 4; n++) {
    const int col = nbase + wcol * 64 + n * 16 + c;
    const float bv = bias[col];
    if (!PROJ) {
#pragma unroll
      for (int m = 0; m < 4; m++) {
        const int r0 = mbase + wrow * 64 + m * 16 + g * 4;
#pragma unroll
        for (int j = 0; j < 4; j++)
          outf[(size_t)(r0 + j) * ND + col] = acc[m][n][j] + bv;
      }
    } else if (z == 2) {
      const int h = col >> 6, dd = col & 63;
#pragma unroll
      for (int m = 0; m < 4; m++) {
        const int r0 = mbase + wrow * 64 + m * 16 + g * 4;
        const int bb = r0 >> 10, t = r0 & (NT - 1);
        ushort4v y;
#pragma unroll
        for (int j = 0; j < 4; j++) y[j] = f2bf(acc[m][n][j] + bv);
        *(ushort4v*)&vhT[((size_t)(bb * NH + h) * NDH + dd) * NT + t] = y;
      }
    } else {
      unsigned short* outb = (z == 0) ? qhb : khb;
      const float scale = (z == 0) ? 0.125f : 1.0f;
#pragma unroll
      for (int m = 0; m < 4; m++) {
        const int r0 = mbase + wrow * 64 + m * 16 + g * 4;
#pragma unroll
        for (int j = 0; j < 4; j++)
          outb[(size_t)(r0 + j) * ND + col] = f2bf((acc[m][n][j] + bv) * scale);
      }
    }
  }
}

// ---------------------------------------------------------------------------
// Flash attention, swapped-QK^T form. 4 waves x 32 q-rows = 128 q/block.
// S^T = mfma(K, Q): lane holds 16 t-values for q = lane&15 (+16*half) ->
// softmax reduce = in-lane tree + 2 shfl_xor. V is pre-transposed (vhT), so
// PV computes O^T = mfma(Vt, P^T) with contiguous LDS reads. K/V double-
// buffered via global_load_lds with pre-swizzled source (chunk ^= row&7).
// ---------------------------------------------------------------------------
__global__ __launch_bounds__(256) void attn_kernel(
    const unsigned short* __restrict__ qh, const unsigned short* __restrict__ kh,
    const unsigned short* __restrict__ vhT, const unsigned int* __restrict__ mask,
    unsigned short* __restrict__ ao) {
  __shared__ __align__(16) unsigned short Ks[2][64 * 64];
  __shared__ __align__(16) unsigned short Vs[2][64 * 64];
  __shared__ __align__(16) unsigned short Ps[4][32][72];
  const int tid = threadIdx.x, lane = tid & 63, w = tid >> 6;
  const int c = lane & 15, g = lane >> 4;
  const int l8 = lane >> 3, l7 = lane & 7, csw = l7 ^ l8;
  const int qb = blockIdx.x * 128;
  const int b = blockIdx.y / NH, h = blockIdx.y % NH;
  const size_t kbase = (size_t)b * NT * ND + h * NDH;
  const size_t vbase = (size_t)(b * NH + h) * NDH * NT;

  // Q fragments (B operand): 32 q-rows per wave, scaled 1/8 already
  short8 aq[2][2];
#pragma unroll
  for (int half = 0; half < 2; half++) {
    size_t qrow = (size_t)(b * NL + qb + w * 32 + half * 16 + c) * ND + h * NDH;
#pragma unroll
    for (int ks = 0; ks < 2; ks++)
      aq[half][ks] = *(const short8*)&qh[qrow + ks * 32 + g * 8];
  }

  f32x4 o[2][4];
#pragma unroll
  for (int half = 0; half < 2; half++)
#pragma unroll
    for (int f = 0; f < 4; f++) o[half][f] = (f32x4){0.f, 0.f, 0.f, 0.f};
  float mr[2] = {-1e30f, -1e30f}, lr[2] = {0.f, 0.f};

  // prologue: stage tile 0
#pragma unroll
  for (int it = 0; it < 2; it++) {
    int r = w * 16 + it * 8 + l8;
    gll16(&kh[kbase + (size_t)r * ND + csw * 8], &Ks[0][(w * 16 + it * 8) * 64]);
    gll16(&vhT[vbase + (size_t)r * NT + csw * 8], &Vs[0][(w * 16 + it * 8) * 64]);
  }
  __syncthreads();

  for (int t0 = 0; t0 < NT; t0 += 64) {
    const int cur = (t0 >> 6) & 1;
    if (t0 + 64 < NT) {  // prefetch next tile into the other buffer
#pragma unroll
      for (int it = 0; it < 2; it++) {
        int r = w * 16 + it * 8 + l8;
        gll16(&kh[kbase + (size_t)(t0 + 64 + r) * ND + csw * 8],
              &Ks[cur ^ 1][(w * 16 + it * 8) * 64]);
        gll16(&vhT[vbase + (size_t)r * NT + (t0 + 64) + csw * 8],
              &Vs[cur ^ 1][(w * 16 + it * 8) * 64]);
      }
    }

    // ---- S^T = K Q (rows = t, cols = q)
    f32x4 s[2][4];
#pragma unroll
    for (int half = 0; half < 2; half++)
#pragma unroll
      for (int n = 0; n < 4; n++) s[half][n] = (f32x4){0.f, 0.f, 0.f, 0.f};
#pragma unroll
    for (int ks = 0; ks < 2; ks++)
#pragma unroll
      for (int n = 0; n < 4; n++) {
        short8 ak = *(const short8*)&Ks[cur][(n * 16 + c) * 64 + (((ks * 4 + g) ^ (c & 7)) * 8)];
        s[0][n] = __builtin_amdgcn_mfma_f32_16x16x32_bf16(ak, aq[0][ks], s[0][n], 0, 0, 0);
        s[1][n] = __builtin_amdgcn_mfma_f32_16x16x32_bf16(ak, aq[1][ks], s[1][n], 0, 0, 0);
      }

    // ---- mask (t = n*16 + g*4 + j, uniform over q)
#pragma unroll
    for (int n = 0; n < 4; n++) {
      uint4v mm = *(const uint4v*)&mask[(size_t)b * NT + t0 + n * 16 + g * 4];
#pragma unroll
      for (int j = 0; j < 4; j++)
        if (mm[j]) { s[0][n][j] = -INFINITY; s[1][n][j] = -INFINITY; }
    }

    // ---- online softmax (per 16-q half); t is register-local
#pragma unroll
    for (int half = 0; half < 2; half++) {
      float m01 = fmaxf(fmaxf(s[half][0][0], s[half][0][1]), fmaxf(s[half][0][2], s[half][0][3]));
      float m23 = fmaxf(fmaxf(s[half][1][0], s[half][1][1]), fmaxf(s[half][1][2], s[half][1][3]));
      float m45 = fmaxf(fmaxf(s[half][2][0], s[half][2][1]), fmaxf(s[half][2][2], s[half][2][3]));
      float m67 = fmaxf(fmaxf(s[half][3][0], s[half][3][1]), fmaxf(s[half][3][2], s[half][3][3]));
      float mt = fmaxf(fmaxf(m01, m23), fmaxf(m45, m67));
      mt = fmaxf(mt, __shfl_xor(mt, 16, 64));
      mt = fmaxf(mt, __shfl_xor(mt, 32, 64));
      float mnew = fmaxf(mr[half], mt);
      float alpha = __expf(mr[half] - mnew);
      mr[half] = mnew;
      float rs = 0.f;
#pragma unroll
      for (int n = 0; n < 4; n++)
#pragma unroll
        for (int j = 0; j < 4; j++) {
          float p = __expf(s[half][n][j] - mnew);
          s[half][n][j] = p;
          rs += p;
        }
      rs += __shfl_xor(rs, 16, 64);
      rs += __shfl_xor(rs, 32, 64);
      lr[half] = lr[half] * alpha + rs;
#pragma unroll
      for (int f = 0; f < 4; f++)
#pragma unroll
        for (int j = 0; j < 4; j++) o[half][f][j] *= alpha;
      // pack P (bf16) into wave-private Ps[q][t]
      unsigned* pr = (unsigned*)&Ps[w][half * 16 + c][0];
#pragma unroll
      for (int n = 0; n < 4; n++) {
        pr[n * 8 + g * 2]     = pk2(s[half][n][0], s[half][n][1]);
        pr[n * 8 + g * 2 + 1] = pk2(s[half][n][2], s[half][n][3]);
      }
    }

    // ---- O^T += Vt P^T  (same-wave Ps reuse; no barrier needed)
#pragma unroll
    for (int ks = 0; ks < 2; ks++) {
      short8 bp0 = *(const short8*)&Ps[w][c][ks * 32 + g * 8];
      short8 bp1 = *(const short8*)&Ps[w][16 + c][ks * 32 + g * 8];
#pragma unroll
      for (int f = 0; f < 4; f++) {
        short8 av = *(const short8*)&Vs[cur][(f * 16 + c) * 64 + (((ks * 4 + g) ^ (c & 7)) * 8)];
        o[0][f] = __builtin_amdgcn_mfma_f32_16x16x32_bf16(av, bp0, o[0][f], 0, 0, 0);
        o[1][f] = __builtin_amdgcn_mfma_f32_16x16x32_bf16(av, bp1, o[1][f], 0, 0, 0);
      }
    }
    __syncthreads();
  }

  // ---- epilogue: O^T / l -> bf16 (lane writes 4 consecutive d per frag)
#pragma unroll
  for (int half = 0; half < 2; half++) {
    float inv = 1.f / lr[half];
    size_t row = (size_t)(b * NL + qb + w * 32 + half * 16 + c) * ND + h * NDH;
#pragma unroll
    for (int f = 0; f < 4; f++) {
      ushort4v y;
#pragma unroll
      for (int j = 0; j < 4; j++) y[j] = f2bf(o[half][f][j] * inv);
      *(ushort4v*)&ao[row + f * 16 + g * 4] = y;
    }
  }
}

// ---------------------------------------------------------------------------
extern "C" void kernel_launch(void* const* d_in, const int* in_sizes, int n_in,
                              void* d_out, int out_size, void* d_ws, size_t ws_size,
                              hipStream_t stream) {
  const float* q  = (const float*)d_in[0];
  const float* k  = (const float*)d_in[1];
  const float* v  = (const float*)d_in[2];
  // d_in[3] = pairwise_locs: unused in the reference forward path
  const unsigned int* mask = (const unsigned int*)d_in[4];
  const float* Wq = (const float*)d_in[5];
  const float* bq = (const float*)d_in[6];
  const float* Wk = (const float*)d_in[7];
  const float* bk = (const float*)d_in[8];
  const float* Wv = (const float*)d_in[9];
  const float* bv = (const float*)d_in[10];
  const float* Wo = (const float*)d_in[11];
  const float* bo = (const float*)d_in[12];
  float* out = (float*)d_out;

  unsigned short* ws  = (unsigned short*)d_ws;
  unsigned short* Wt  = ws;                          // 4 * 768*768
  unsigned short* qhb = Wt + (size_t)4 * ND * ND;    // 8192*768
  unsigned short* khb = qhb + (size_t)NM * ND;
  unsigned short* vhT = khb + (size_t)NM * ND;       // [(b*NH+h)*64+d][1024]
  unsigned short* aob = vhT + (size_t)NM * ND;

  wt_kernel<<<dim3(ND / 32, ND / 32, 4), 256, 0, stream>>>(Wq, Wk, Wv, Wo, Wt);

  gemm_kernel<1><<<dim3(NM / 128, ND / 128, 3), 256, 0, stream>>>(
      q, k, v, nullptr, Wt, bq, bk, bv, bo, qhb, khb, vhT, nullptr);

  attn_kernel<<<dim3(NL / 128, NB * NH), 256, 0, stream>>>(qhb, khb, vhT, mask, aob);

  gemm_kernel<0><<<dim3(NM / 128, ND / 128, 1), 256, 0, stream>>>(
      nullptr, nullptr, nullptr, aob, Wt, bq, bk, bv, bo, nullptr, nullptr, nullptr, out);
}